// Round 1
// baseline (440.699 us; speedup 1.0000x reference)
//
#include <hip/hip_runtime.h>

// RasterizeGaussians: P=8192 gaussians -> 3x256x256 fp32 image.
// Stage 1: preprocess (mean2d, conic, depth)          [32 x 256]
// Stage 2: O(P^2) rank sort + scatter + tile bitmask  [128 x 64]
// Stage 3: per-tile rasterize, rank-ordered bit walk  [256 x 256]

#define PN 8192
#define IH 256
#define IW 256
#define NCHUNK (PN / 256)      // 32 chunks of 256 gaussians
#define MASK_WORDS (PN / 64)   // 128 u64 words per tile
#define NTILES 256             // 16x16 tiles of 16x16 px

// ws float layout:
//  pre:    depth[PN] mx[PN] my[PN] cA[PN] cB[PN] cC[PN]        (6*PN)
//  sorted: mx my cA cB cC op r g b                              (9*PN)
//  mask:   u64[NTILES][MASK_WORDS] at byte offset 15*PN*4       (256 KB)
#define WS_SORTED (6 * PN)
#define WS_MASK_BYTE_OFF (15 * PN * 4)

__global__ __launch_bounds__(256) void preprocess_kernel(
    const float* __restrict__ means, const float* __restrict__ scales,
    const float* __restrict__ rots, const float* __restrict__ V,
    const float* __restrict__ Pm, float* __restrict__ ws)
{
    int i = blockIdx.x * 256 + threadIdx.x;
    if (i >= PN) return;

    float mx3 = means[3 * i], my3 = means[3 * i + 1], mz3 = means[3 * i + 2];
    float qr = rots[4 * i], qx = rots[4 * i + 1], qy = rots[4 * i + 2], qz = rots[4 * i + 3];
    float qn = 1.0f / sqrtf(qr * qr + qx * qx + qy * qy + qz * qz);
    float r = qr * qn, x = qx * qn, y = qy * qn, z = qz * qn;

    float R00 = 1.f - 2.f * (y * y + z * z), R01 = 2.f * (x * y - r * z), R02 = 2.f * (x * z + r * y);
    float R10 = 2.f * (x * y + r * z), R11 = 1.f - 2.f * (x * x + z * z), R12 = 2.f * (y * z - r * x);
    float R20 = 2.f * (x * z - r * y), R21 = 2.f * (y * z + r * x), R22 = 1.f - 2.f * (x * x + y * y);

    float s0 = scales[3 * i];     s0 *= s0;
    float s1 = scales[3 * i + 1]; s1 *= s1;
    float s2 = scales[3 * i + 2]; s2 *= s2;

    // Sigma = R diag(s2) R^T (symmetric)
    float Sg[3][3];
    Sg[0][0] = R00 * R00 * s0 + R01 * R01 * s1 + R02 * R02 * s2;
    Sg[0][1] = R00 * R10 * s0 + R01 * R11 * s1 + R02 * R12 * s2;
    Sg[0][2] = R00 * R20 * s0 + R01 * R21 * s1 + R02 * R22 * s2;
    Sg[1][1] = R10 * R10 * s0 + R11 * R11 * s1 + R12 * R12 * s2;
    Sg[1][2] = R10 * R20 * s0 + R11 * R21 * s1 + R12 * R22 * s2;
    Sg[2][2] = R20 * R20 * s0 + R21 * R21 * s1 + R22 * R22 * s2;
    Sg[1][0] = Sg[0][1]; Sg[2][0] = Sg[0][2]; Sg[2][1] = Sg[1][2];

    // p_view = hom @ V (row-vector convention), p_hom = hom @ Pm
    float pv0 = mx3 * V[0] + my3 * V[4] + mz3 * V[8]  + V[12];
    float pv1 = mx3 * V[1] + my3 * V[5] + mz3 * V[9]  + V[13];
    float pv2 = mx3 * V[2] + my3 * V[6] + mz3 * V[10] + V[14];
    float ph0 = mx3 * Pm[0] + my3 * Pm[4] + mz3 * Pm[8]  + Pm[12];
    float ph1 = mx3 * Pm[1] + my3 * Pm[5] + mz3 * Pm[9]  + Pm[13];
    float ph3 = mx3 * Pm[3] + my3 * Pm[7] + mz3 * Pm[11] + Pm[15];
    float pw = 1.0f / (ph3 + 1e-7f);
    float ndcx = ph0 * pw, ndcy = ph1 * pw;
    float m2x = ((ndcx + 1.0f) * (float)IW - 1.0f) * 0.5f;
    float m2y = ((ndcy + 1.0f) * (float)IH - 1.0f) * 0.5f;

    // cov_cam = Rv^T Sigma Rv
    float Rv[3][3];
#pragma unroll
    for (int rr = 0; rr < 3; ++rr)
#pragma unroll
        for (int cc2 = 0; cc2 < 3; ++cc2) Rv[rr][cc2] = V[rr * 4 + cc2];
    float M[3][3];
#pragma unroll
    for (int j = 0; j < 3; ++j)
#pragma unroll
        for (int l = 0; l < 3; ++l)
            M[j][l] = Sg[j][0] * Rv[0][l] + Sg[j][1] * Rv[1][l] + Sg[j][2] * Rv[2][l];
    float cc[3][3];
#pragma unroll
    for (int ii = 0; ii < 3; ++ii)
#pragma unroll
        for (int l = 0; l < 3; ++l)
            cc[ii][l] = Rv[0][ii] * M[0][l] + Rv[1][ii] * M[1][l] + Rv[2][ii] * M[2][l];

    const float FX = (float)IW / (2.0f * 0.5f);  // 256
    const float FY = (float)IH / (2.0f * 0.5f);
    float tz = pv2;
    float itz = 1.0f / tz;
    float limx = 1.3f * 0.5f, limy = 1.3f * 0.5f;
    float txz = fminf(fmaxf(pv0 * itz, -limx), limx);
    float tyz = fminf(fmaxf(pv1 * itz, -limy), limy);
    float tx = txz * tz, ty = tyz * tz;
    float J00 = FX * itz, J02 = -FX * tx * itz * itz;
    float J11 = FY * itz, J12 = -FY * ty * itz * itz;

    float u00 = J00 * cc[0][0] + J02 * cc[2][0];
    float u01 = J00 * cc[0][1] + J02 * cc[2][1];
    float u02 = J00 * cc[0][2] + J02 * cc[2][2];
    float u10 = J11 * cc[1][0] + J12 * cc[2][0];
    float u11 = J11 * cc[1][1] + J12 * cc[2][1];
    float u12 = J11 * cc[1][2] + J12 * cc[2][2];
    float cov00 = u00 * J00 + u02 * J02;
    float cov01 = u01 * J11 + u02 * J12;
    float cov11 = u11 * J11 + u12 * J12;

    float a = cov00 + 0.3f;
    float b = cov01;
    float c = cov11 + 0.3f;
    float det = a * c - b * b;
    float idet = 1.0f / det;

    ws[i]          = pv2;          // depth
    ws[PN + i]     = m2x;
    ws[2 * PN + i] = m2y;
    ws[3 * PN + i] = c * idet;     // cA (multiplies dx^2)
    ws[4 * PN + i] = -b * idet;    // cB (cross)
    ws[5 * PN + i] = a * idet;     // cC (multiplies dy^2)
}

__global__ __launch_bounds__(64) void sort_scatter_kernel(
    const float* __restrict__ colors, const float* __restrict__ ops,
    float* __restrict__ ws)
{
    __shared__ float sdep[PN];  // 32 KB
    float4* sd4 = (float4*)sdep;
    const float4* gd4 = (const float4*)ws;  // pre_depth
    for (int t = threadIdx.x; t < PN / 4; t += 64) sd4[t] = gd4[t];
    __syncthreads();

    int i = blockIdx.x * 64 + threadIdx.x;
    float di = sdep[i];
    int rank = 0;
#pragma unroll 8
    for (int j4 = 0; j4 < PN / 4; ++j4) {
        float4 d = sd4[j4];
        int jb = j4 * 4;
        rank += (d.x < di) || (d.x == di && (jb    ) < i);
        rank += (d.y < di) || (d.y == di && (jb + 1) < i);
        rank += (d.z < di) || (d.z == di && (jb + 2) < i);
        rank += (d.w < di) || (d.w == di && (jb + 3) < i);
    }

    float mx = ws[PN + i], my = ws[2 * PN + i];
    float cA = ws[3 * PN + i], cB = ws[4 * PN + i], cC = ws[5 * PN + i];
    float* so = ws + WS_SORTED;
    so[rank]          = mx;
    so[PN + rank]     = my;
    so[2 * PN + rank] = cA;
    so[3 * PN + rank] = cB;
    so[4 * PN + rank] = cC;
    so[5 * PN + rank] = ops[i];
    so[6 * PN + rank] = colors[3 * i];
    so[7 * PN + rank] = colors[3 * i + 1];
    so[8 * PN + rank] = colors[3 * i + 2];

    // tile mask: conservative bbox of {power >= -5.6} ellipse (+1 px margin)
    float q = cA * cC - cB * cB;          // = 1/det(cov2d) > 0
    float acov = cC / q;                  // cov2d a
    float ccov = cA / q;                  // cov2d c
    float ex = sqrtf(fmaxf(11.2f * acov, 0.0f)) + 1.0f;
    float ey = sqrtf(fmaxf(11.2f * ccov, 0.0f)) + 1.0f;
    int x0 = max(0,  (int)floorf((mx - ex) * (1.0f / 16.0f)));
    int x1 = min(15, (int)floorf((mx + ex) * (1.0f / 16.0f)));
    int y0 = max(0,  (int)floorf((my - ey) * (1.0f / 16.0f)));
    int y1 = min(15, (int)floorf((my + ey) * (1.0f / 16.0f)));

    unsigned long long* mask =
        (unsigned long long*)((char*)ws + WS_MASK_BYTE_OFF);
    unsigned long long bit = 1ull << (rank & 63);
    int word = rank >> 6;
    for (int ty = y0; ty <= y1; ++ty)
        for (int txi = x0; txi <= x1; ++txi)
            atomicOr(&mask[(ty * 16 + txi) * MASK_WORDS + word], bit);
}

__global__ __launch_bounds__(256) void raster_kernel(
    const float* __restrict__ ws, const float* __restrict__ bg,
    float* __restrict__ out)
{
    __shared__ float smx[256], smy[256], sca[256], scb[256], scc[256];
    __shared__ float sop[256], sr[256], sg[256], sb[256];

    int tid = threadIdx.x;
    int lx = tid & 15, ly = tid >> 4;
    int tileX = blockIdx.x & 15, tileY = blockIdx.x >> 4;
    int px = tileX * 16 + lx, py = tileY * 16 + ly;
    float pxf = (float)px, pyf = (float)py;

    const float* so = ws + WS_SORTED;
    const unsigned long long* tmask =
        (const unsigned long long*)((const char*)ws + WS_MASK_BYTE_OFF) +
        blockIdx.x * MASK_WORDS;

    float T = 1.0f, ar = 0.0f, ag = 0.0f, ab = 0.0f;

    for (int chunk = 0; chunk < NCHUNK; ++chunk) {
        unsigned long long w0 = tmask[chunk * 4 + 0];
        unsigned long long w1 = tmask[chunk * 4 + 1];
        unsigned long long w2 = tmask[chunk * 4 + 2];
        unsigned long long w3 = tmask[chunk * 4 + 3];
        if (!(w0 | w1 | w2 | w3)) continue;  // block-uniform

        __syncthreads();
        int g = chunk * 256 + tid;
        smx[tid] = so[g];
        smy[tid] = so[PN + g];
        sca[tid] = so[2 * PN + g];
        scb[tid] = so[3 * PN + g];
        scc[tid] = so[4 * PN + g];
        sop[tid] = so[5 * PN + g];
        sr[tid]  = so[6 * PN + g];
        sg[tid]  = so[7 * PN + g];
        sb[tid]  = so[8 * PN + g];
        __syncthreads();

        unsigned long long wv[4] = {w0, w1, w2, w3};
#pragma unroll
        for (int k = 0; k < 4; ++k) {
            unsigned long long w = wv[k];
            while (w) {
                int b = __ffsll(w) - 1;
                w &= (w - 1);
                int j = k * 64 + b;
                float dx = smx[j] - pxf;
                float dy = smy[j] - pyf;
                float power = -0.5f * (sca[j] * dx * dx + scc[j] * dy * dy) -
                              scb[j] * dx * dy;
                if (power > 0.0f || power < -5.6f) continue;
                float alpha = fminf(0.99f, sop[j] * __expf(power));
                if (alpha < (1.0f / 255.0f)) continue;
                float wgt = alpha * T;
                ar = fmaf(wgt, sr[j], ar);
                ag = fmaf(wgt, sg[j], ag);
                ab = fmaf(wgt, sb[j], ab);
                T *= (1.0f - alpha);
            }
        }
        if (__syncthreads_and(T < 1e-4f)) break;  // residual <= 1e-4 << 1.8e-2
    }

    int pidx = py * IW + px;
    out[pidx]               = ar + T * bg[0];
    out[IH * IW + pidx]     = ag + T * bg[1];
    out[2 * IH * IW + pidx] = ab + T * bg[2];
}

extern "C" void kernel_launch(void* const* d_in, const int* in_sizes, int n_in,
                              void* d_out, int out_size, void* d_ws, size_t ws_size,
                              hipStream_t stream) {
    const float* means  = (const float*)d_in[0];
    const float* colors = (const float*)d_in[1];
    const float* ops    = (const float*)d_in[2];
    const float* scales = (const float*)d_in[3];
    const float* rots   = (const float*)d_in[4];
    const float* bg     = (const float*)d_in[5];
    const float* viewm  = (const float*)d_in[6];
    const float* projm  = (const float*)d_in[7];
    float* out = (float*)d_out;
    float* ws  = (float*)d_ws;

    void* mask = (void*)((char*)d_ws + WS_MASK_BYTE_OFF);
    hipMemsetAsync(mask, 0, NTILES * MASK_WORDS * 8, stream);

    hipLaunchKernelGGL(preprocess_kernel, dim3(PN / 256), dim3(256), 0, stream,
                       means, scales, rots, viewm, projm, ws);
    hipLaunchKernelGGL(sort_scatter_kernel, dim3(PN / 64), dim3(64), 0, stream,
                       colors, ops, ws);
    hipLaunchKernelGGL(raster_kernel, dim3(NTILES), dim3(256), 0, stream,
                       ws, bg, out);
}

// Round 2
// 135.566 us; speedup vs baseline: 3.2508x; 3.2508x over previous
//
#include <hip/hip_runtime.h>

// RasterizeGaussians: P=8192 gaussians -> 3x256x256 fp32 image.
// Stage 1: preprocess -> per-gaussian record + tile bbox      [32 x 256]
// Stage 2: O(P^2) rank sort, wave-per-4-gaussians, permute    [512 x 256]
// Stage 3: per 8x8-px tile (1 wave): ballot mask -> LDS compact -> walk [1024 x 64]

#define PN 8192
#define IH 256
#define IW 256

// ws float layout:
//  depth  [0, PN)
//  preA f4 [PN, 5PN)      (mx, my, cA, cB)
//  preB f4 [5PN, 9PN)     (cC, op, r, g)
//  preb    [9PN, 10PN)    (b color)
//  prebox  [10PN, 11PN)   (packed u32 tile bbox, 8px tiles: x0|x1<<8|y0<<16|y1<<24)
//  sA f4   [11PN, 15PN)
//  sB f4   [15PN, 19PN)
//  sb      [19PN, 20PN)
//  sbox    [20PN, 21PN)
// total 21*PN*4 = 672 KB

__global__ __launch_bounds__(256) void preprocess_kernel(
    const float* __restrict__ means, const float* __restrict__ colors,
    const float* __restrict__ ops, const float* __restrict__ scales,
    const float* __restrict__ rots, const float* __restrict__ V,
    const float* __restrict__ Pm, float* __restrict__ ws)
{
    int i = blockIdx.x * 256 + threadIdx.x;
    if (i >= PN) return;

    float mx3 = means[3 * i], my3 = means[3 * i + 1], mz3 = means[3 * i + 2];
    float qr = rots[4 * i], qx = rots[4 * i + 1], qy = rots[4 * i + 2], qz = rots[4 * i + 3];
    float qn = 1.0f / sqrtf(qr * qr + qx * qx + qy * qy + qz * qz);
    float r = qr * qn, x = qx * qn, y = qy * qn, z = qz * qn;

    float R00 = 1.f - 2.f * (y * y + z * z), R01 = 2.f * (x * y - r * z), R02 = 2.f * (x * z + r * y);
    float R10 = 2.f * (x * y + r * z), R11 = 1.f - 2.f * (x * x + z * z), R12 = 2.f * (y * z - r * x);
    float R20 = 2.f * (x * z - r * y), R21 = 2.f * (y * z + r * x), R22 = 1.f - 2.f * (x * x + y * y);

    float s0 = scales[3 * i];     s0 *= s0;
    float s1 = scales[3 * i + 1]; s1 *= s1;
    float s2 = scales[3 * i + 2]; s2 *= s2;

    float Sg[3][3];
    Sg[0][0] = R00 * R00 * s0 + R01 * R01 * s1 + R02 * R02 * s2;
    Sg[0][1] = R00 * R10 * s0 + R01 * R11 * s1 + R02 * R12 * s2;
    Sg[0][2] = R00 * R20 * s0 + R01 * R21 * s1 + R02 * R22 * s2;
    Sg[1][1] = R10 * R10 * s0 + R11 * R11 * s1 + R12 * R12 * s2;
    Sg[1][2] = R10 * R20 * s0 + R11 * R21 * s1 + R12 * R22 * s2;
    Sg[2][2] = R20 * R20 * s0 + R21 * R21 * s1 + R22 * R22 * s2;
    Sg[1][0] = Sg[0][1]; Sg[2][0] = Sg[0][2]; Sg[2][1] = Sg[1][2];

    float pv0 = mx3 * V[0] + my3 * V[4] + mz3 * V[8]  + V[12];
    float pv1 = mx3 * V[1] + my3 * V[5] + mz3 * V[9]  + V[13];
    float pv2 = mx3 * V[2] + my3 * V[6] + mz3 * V[10] + V[14];
    float ph0 = mx3 * Pm[0] + my3 * Pm[4] + mz3 * Pm[8]  + Pm[12];
    float ph1 = mx3 * Pm[1] + my3 * Pm[5] + mz3 * Pm[9]  + Pm[13];
    float ph3 = mx3 * Pm[3] + my3 * Pm[7] + mz3 * Pm[11] + Pm[15];
    float pw = 1.0f / (ph3 + 1e-7f);
    float m2x = ((ph0 * pw + 1.0f) * (float)IW - 1.0f) * 0.5f;
    float m2y = ((ph1 * pw + 1.0f) * (float)IH - 1.0f) * 0.5f;

    float Rv[3][3];
#pragma unroll
    for (int rr = 0; rr < 3; ++rr)
#pragma unroll
        for (int cc2 = 0; cc2 < 3; ++cc2) Rv[rr][cc2] = V[rr * 4 + cc2];
    float M[3][3];
#pragma unroll
    for (int j = 0; j < 3; ++j)
#pragma unroll
        for (int l = 0; l < 3; ++l)
            M[j][l] = Sg[j][0] * Rv[0][l] + Sg[j][1] * Rv[1][l] + Sg[j][2] * Rv[2][l];
    float cc[3][3];
#pragma unroll
    for (int ii = 0; ii < 3; ++ii)
#pragma unroll
        for (int l = 0; l < 3; ++l)
            cc[ii][l] = Rv[0][ii] * M[0][l] + Rv[1][ii] * M[1][l] + Rv[2][ii] * M[2][l];

    const float FX = 256.0f, FY = 256.0f;
    float tz = pv2;
    float itz = 1.0f / tz;
    float limx = 0.65f, limy = 0.65f;
    float txz = fminf(fmaxf(pv0 * itz, -limx), limx);
    float tyz = fminf(fmaxf(pv1 * itz, -limy), limy);
    float tx = txz * tz, ty = tyz * tz;
    float J00 = FX * itz, J02 = -FX * tx * itz * itz;
    float J11 = FY * itz, J12 = -FY * ty * itz * itz;

    float u00 = J00 * cc[0][0] + J02 * cc[2][0];
    float u01 = J00 * cc[0][1] + J02 * cc[2][1];
    float u02 = J00 * cc[0][2] + J02 * cc[2][2];
    float u11 = J11 * cc[1][1] + J12 * cc[2][1];
    float u12 = J11 * cc[1][2] + J12 * cc[2][2];
    float cov00 = u00 * J00 + u02 * J02;
    float cov01 = u01 * J11 + u02 * J12;
    float cov11 = u11 * J11 + u12 * J12;

    float a = cov00 + 0.3f;
    float b = cov01;
    float c = cov11 + 0.3f;
    float det = a * c - b * b;
    float idet = 1.0f / det;
    float cA = c * idet;    // dx^2 coef
    float cB = -b * idet;   // cross coef
    float cC = a * idet;    // dy^2 coef

    // tile bbox: |dx| <= sqrt(11.2*a), |dy| <= sqrt(11.2*c) covers power >= -5.6;
    // o <= 0.95 => alpha < 1/255 outside (exact gate in raster kills any slack).
    float ex = sqrtf(11.2f * a);
    float ey = sqrtf(11.2f * c);
    int x0 = max(0,  (int)floorf((m2x - ex) * 0.125f));
    int x1 = min(31, (int)floorf((m2x + ex) * 0.125f));
    int y0 = max(0,  (int)floorf((m2y - ey) * 0.125f));
    int y1 = min(31, (int)floorf((m2y + ey) * 0.125f));
    x0 = min(x0, 31); y0 = min(y0, 31); x1 = max(x1, 0); y1 = max(y1, 0);
    unsigned box = (unsigned)x0 | ((unsigned)x1 << 8) | ((unsigned)y0 << 16) | ((unsigned)y1 << 24);

    ws[i] = pv2;  // depth
    float4* preA = (float4*)(ws + PN);
    float4* preB = (float4*)(ws + 5 * PN);
    preA[i] = make_float4(m2x, m2y, cA, cB);
    preB[i] = make_float4(cC, ops[i], colors[3 * i], colors[3 * i + 1]);
    ws[9 * PN + i] = colors[3 * i + 2];
    ((unsigned*)(ws + 10 * PN))[i] = box;
}

__global__ __launch_bounds__(256) void sort_scatter_kernel(float* __restrict__ ws)
{
    const float* dep = ws;
    const float4* d4 = (const float4*)ws;
    int lane = threadIdx.x & 63;
    int wid = threadIdx.x >> 6;
    int gbase = blockIdx.x * 16 + wid * 4;   // 512 blocks * 4 waves * 4 gaussians

    float di0 = dep[gbase], di1 = dep[gbase + 1], di2 = dep[gbase + 2], di3 = dep[gbase + 3];
    int r0 = 0, r1 = 0, r2 = 0, r3 = 0;
#pragma unroll 4
    for (int k = 0; k < 32; ++k) {
        int j4 = k * 64 + lane;
        float4 d = d4[j4];
        int jb = j4 * 4;
        r0 += (d.x < di0) || (d.x == di0 && (jb    ) < gbase);
        r0 += (d.y < di0) || (d.y == di0 && (jb + 1) < gbase);
        r0 += (d.z < di0) || (d.z == di0 && (jb + 2) < gbase);
        r0 += (d.w < di0) || (d.w == di0 && (jb + 3) < gbase);
        r1 += (d.x < di1) || (d.x == di1 && (jb    ) < gbase + 1);
        r1 += (d.y < di1) || (d.y == di1 && (jb + 1) < gbase + 1);
        r1 += (d.z < di1) || (d.z == di1 && (jb + 2) < gbase + 1);
        r1 += (d.w < di1) || (d.w == di1 && (jb + 3) < gbase + 1);
        r2 += (d.x < di2) || (d.x == di2 && (jb    ) < gbase + 2);
        r2 += (d.y < di2) || (d.y == di2 && (jb + 1) < gbase + 2);
        r2 += (d.z < di2) || (d.z == di2 && (jb + 2) < gbase + 2);
        r2 += (d.w < di2) || (d.w == di2 && (jb + 3) < gbase + 2);
        r3 += (d.x < di3) || (d.x == di3 && (jb    ) < gbase + 3);
        r3 += (d.y < di3) || (d.y == di3 && (jb + 1) < gbase + 3);
        r3 += (d.z < di3) || (d.z == di3 && (jb + 2) < gbase + 3);
        r3 += (d.w < di3) || (d.w == di3 && (jb + 3) < gbase + 3);
    }
#pragma unroll
    for (int off = 1; off < 64; off <<= 1) {
        r0 += __shfl_xor(r0, off);
        r1 += __shfl_xor(r1, off);
        r2 += __shfl_xor(r2, off);
        r3 += __shfl_xor(r3, off);
    }
    if (lane < 4) {
        int rk = (lane == 0) ? r0 : (lane == 1) ? r1 : (lane == 2) ? r2 : r3;
        int i = gbase + lane;
        const float4* preA = (const float4*)(ws + PN);
        const float4* preB = (const float4*)(ws + 5 * PN);
        float4* sA = (float4*)(ws + 11 * PN);
        float4* sB = (float4*)(ws + 15 * PN);
        sA[rk] = preA[i];
        sB[rk] = preB[i];
        ws[19 * PN + rk] = ws[9 * PN + i];
        ((unsigned*)(ws + 20 * PN))[rk] = ((const unsigned*)(ws + 10 * PN))[i];
    }
}

__global__ __launch_bounds__(64) void raster_kernel(
    const float* __restrict__ ws, const float* __restrict__ bg,
    float* __restrict__ out)
{
    __shared__ float4 lsA[256];
    __shared__ float4 lsB[256];
    __shared__ float  lsb[256];

    int lane = threadIdx.x;
    int tileX = blockIdx.x & 31, tileY = blockIdx.x >> 5;  // 32x32 tiles of 8x8 px
    int px = tileX * 8 + (lane & 7), py = tileY * 8 + (lane >> 3);
    float pxf = (float)px, pyf = (float)py;

    const float4* sA = (const float4*)(ws + 11 * PN);
    const float4* sB = (const float4*)(ws + 15 * PN);
    const float* sb = ws + 19 * PN;
    const unsigned* sbox = (const unsigned*)(ws + 20 * PN);

    float T = 1.0f, ar = 0.0f, ag = 0.0f, ab = 0.0f;

    for (int chunk = 0; chunk < 32; ++chunk) {
        int base = chunk * 256;
        unsigned long long w[4];
#pragma unroll
        for (int k = 0; k < 4; ++k) {
            unsigned bx = sbox[base + k * 64 + lane];
            bool ov = (tileX >= (int)(bx & 255)) & (tileX <= (int)((bx >> 8) & 255)) &
                      (tileY >= (int)((bx >> 16) & 255)) & (tileY <= (int)(bx >> 24));
            w[k] = __ballot(ov);
        }
        if (!(w[0] | w[1] | w[2] | w[3])) continue;

        // compact surviving gaussians into LDS, rank order preserved
        int pre = 0;
#pragma unroll
        for (int k = 0; k < 4; ++k) {
            unsigned long long wk = w[k];
            if ((wk >> lane) & 1ull) {
                int slot = pre + (int)__popcll(wk & ((1ull << lane) - 1ull));
                int g = base + k * 64 + lane;
                lsA[slot] = sA[g];
                lsB[slot] = sB[g];
                lsb[slot] = sb[g];
            }
            pre += (int)__popcll(wk);
        }
        __syncthreads();  // single wave: cheap; orders LDS writes before reads

        for (int j = 0; j < pre; ++j) {
            float4 A = lsA[j];
            float4 B = lsB[j];
            float bcol = lsb[j];
            float dx = A.x - pxf, dy = A.y - pyf;
            float power = -0.5f * (A.z * dx * dx + B.x * dy * dy) - A.w * dx * dy;
            float alpha = fminf(0.99f, B.y * __expf(power));
            bool skip = (power > 0.0f) | (alpha < (1.0f / 255.0f));
            float a2 = skip ? 0.0f : alpha;
            float wgt = a2 * T;
            ar = fmaf(wgt, B.z, ar);
            ag = fmaf(wgt, B.w, ag);
            ab = fmaf(wgt, bcol, ab);
            T *= (1.0f - a2);
        }
        __syncthreads();  // WAR: next chunk's writes vs this chunk's reads

        if (__all(T < 1e-4f)) break;  // residual <= 1e-4 << 1.8e-2 threshold
    }

    int pidx = py * IW + px;
    out[pidx]               = ar + T * bg[0];
    out[IH * IW + pidx]     = ag + T * bg[1];
    out[2 * IH * IW + pidx] = ab + T * bg[2];
}

extern "C" void kernel_launch(void* const* d_in, const int* in_sizes, int n_in,
                              void* d_out, int out_size, void* d_ws, size_t ws_size,
                              hipStream_t stream) {
    const float* means  = (const float*)d_in[0];
    const float* colors = (const float*)d_in[1];
    const float* ops    = (const float*)d_in[2];
    const float* scales = (const float*)d_in[3];
    const float* rots   = (const float*)d_in[4];
    const float* bg     = (const float*)d_in[5];
    const float* viewm  = (const float*)d_in[6];
    const float* projm  = (const float*)d_in[7];
    float* out = (float*)d_out;
    float* ws  = (float*)d_ws;

    hipLaunchKernelGGL(preprocess_kernel, dim3(PN / 256), dim3(256), 0, stream,
                       means, colors, ops, scales, rots, viewm, projm, ws);
    hipLaunchKernelGGL(sort_scatter_kernel, dim3(PN / 16), dim3(256), 0, stream, ws);
    hipLaunchKernelGGL(raster_kernel, dim3(1024), dim3(64), 0, stream, ws, bg, out);
}

// Round 3
// 112.057 us; speedup vs baseline: 3.9328x; 1.2098x over previous
//
#include <hip/hip_runtime.h>

// RasterizeGaussians: P=8192 gaussians -> 3x256x256 fp32 image.
// Stage 1: preprocess -> per-gaussian record + tile bbox      [32 x 256]
// Stage 2: O(P^2) rank sort, wave-per-4-gaussians, permute    [512 x 256]
// Stage 3: per 8x8-px tile, 4 waves x 8 rank-chunks each,
//          associative segment compose                        [1024 x 256]

#define PN 8192
#define IH 256
#define IW 256

// ws float layout:
//  depth  [0, PN)
//  preA f4 [PN, 5PN)      (mx, my, cA, cB)
//  preB f4 [5PN, 9PN)     (cC, op, r, g)
//  preb    [9PN, 10PN)    (b color)
//  prebox  [10PN, 11PN)   (packed u32 tile bbox, 8px tiles: x0|x1<<8|y0<<16|y1<<24)
//  sA f4   [11PN, 15PN)
//  sB f4   [15PN, 19PN)
//  sb      [19PN, 20PN)
//  sbox    [20PN, 21PN)

__global__ __launch_bounds__(256) void preprocess_kernel(
    const float* __restrict__ means, const float* __restrict__ colors,
    const float* __restrict__ ops, const float* __restrict__ scales,
    const float* __restrict__ rots, const float* __restrict__ V,
    const float* __restrict__ Pm, float* __restrict__ ws)
{
    int i = blockIdx.x * 256 + threadIdx.x;
    if (i >= PN) return;

    float mx3 = means[3 * i], my3 = means[3 * i + 1], mz3 = means[3 * i + 2];
    float qr = rots[4 * i], qx = rots[4 * i + 1], qy = rots[4 * i + 2], qz = rots[4 * i + 3];
    float qn = 1.0f / sqrtf(qr * qr + qx * qx + qy * qy + qz * qz);
    float r = qr * qn, x = qx * qn, y = qy * qn, z = qz * qn;

    float R00 = 1.f - 2.f * (y * y + z * z), R01 = 2.f * (x * y - r * z), R02 = 2.f * (x * z + r * y);
    float R10 = 2.f * (x * y + r * z), R11 = 1.f - 2.f * (x * x + z * z), R12 = 2.f * (y * z - r * x);
    float R20 = 2.f * (x * z - r * y), R21 = 2.f * (y * z + r * x), R22 = 1.f - 2.f * (x * x + y * y);

    float s0 = scales[3 * i];     s0 *= s0;
    float s1 = scales[3 * i + 1]; s1 *= s1;
    float s2 = scales[3 * i + 2]; s2 *= s2;

    float Sg[3][3];
    Sg[0][0] = R00 * R00 * s0 + R01 * R01 * s1 + R02 * R02 * s2;
    Sg[0][1] = R00 * R10 * s0 + R01 * R11 * s1 + R02 * R12 * s2;
    Sg[0][2] = R00 * R20 * s0 + R01 * R21 * s1 + R02 * R22 * s2;
    Sg[1][1] = R10 * R10 * s0 + R11 * R11 * s1 + R12 * R12 * s2;
    Sg[1][2] = R10 * R20 * s0 + R11 * R21 * s1 + R12 * R22 * s2;
    Sg[2][2] = R20 * R20 * s0 + R21 * R21 * s1 + R22 * R22 * s2;
    Sg[1][0] = Sg[0][1]; Sg[2][0] = Sg[0][2]; Sg[2][1] = Sg[1][2];

    float pv0 = mx3 * V[0] + my3 * V[4] + mz3 * V[8]  + V[12];
    float pv1 = mx3 * V[1] + my3 * V[5] + mz3 * V[9]  + V[13];
    float pv2 = mx3 * V[2] + my3 * V[6] + mz3 * V[10] + V[14];
    float ph0 = mx3 * Pm[0] + my3 * Pm[4] + mz3 * Pm[8]  + Pm[12];
    float ph1 = mx3 * Pm[1] + my3 * Pm[5] + mz3 * Pm[9]  + Pm[13];
    float ph3 = mx3 * Pm[3] + my3 * Pm[7] + mz3 * Pm[11] + Pm[15];
    float pw = 1.0f / (ph3 + 1e-7f);
    float m2x = ((ph0 * pw + 1.0f) * (float)IW - 1.0f) * 0.5f;
    float m2y = ((ph1 * pw + 1.0f) * (float)IH - 1.0f) * 0.5f;

    float Rv[3][3];
#pragma unroll
    for (int rr = 0; rr < 3; ++rr)
#pragma unroll
        for (int cc2 = 0; cc2 < 3; ++cc2) Rv[rr][cc2] = V[rr * 4 + cc2];
    float M[3][3];
#pragma unroll
    for (int j = 0; j < 3; ++j)
#pragma unroll
        for (int l = 0; l < 3; ++l)
            M[j][l] = Sg[j][0] * Rv[0][l] + Sg[j][1] * Rv[1][l] + Sg[j][2] * Rv[2][l];
    float cc[3][3];
#pragma unroll
    for (int ii = 0; ii < 3; ++ii)
#pragma unroll
        for (int l = 0; l < 3; ++l)
            cc[ii][l] = Rv[0][ii] * M[0][l] + Rv[1][ii] * M[1][l] + Rv[2][ii] * M[2][l];

    const float FX = 256.0f, FY = 256.0f;
    float tz = pv2;
    float itz = 1.0f / tz;
    float limx = 0.65f, limy = 0.65f;
    float txz = fminf(fmaxf(pv0 * itz, -limx), limx);
    float tyz = fminf(fmaxf(pv1 * itz, -limy), limy);
    float tx = txz * tz, ty = tyz * tz;
    float J00 = FX * itz, J02 = -FX * tx * itz * itz;
    float J11 = FY * itz, J12 = -FY * ty * itz * itz;

    float u00 = J00 * cc[0][0] + J02 * cc[2][0];
    float u01 = J00 * cc[0][1] + J02 * cc[2][1];
    float u02 = J00 * cc[0][2] + J02 * cc[2][2];
    float u11 = J11 * cc[1][1] + J12 * cc[2][1];
    float u12 = J11 * cc[1][2] + J12 * cc[2][2];
    float cov00 = u00 * J00 + u02 * J02;
    float cov01 = u01 * J11 + u02 * J12;
    float cov11 = u11 * J11 + u12 * J12;

    float a = cov00 + 0.3f;
    float b = cov01;
    float c = cov11 + 0.3f;
    float det = a * c - b * b;
    float idet = 1.0f / det;
    float cA = c * idet;    // dx^2 coef
    float cB = -b * idet;   // cross coef
    float cC = a * idet;    // dy^2 coef

    float ex = sqrtf(11.2f * a);
    float ey = sqrtf(11.2f * c);
    int x0 = max(0,  (int)floorf((m2x - ex) * 0.125f));
    int x1 = min(31, (int)floorf((m2x + ex) * 0.125f));
    int y0 = max(0,  (int)floorf((m2y - ey) * 0.125f));
    int y1 = min(31, (int)floorf((m2y + ey) * 0.125f));
    x0 = min(x0, 31); y0 = min(y0, 31); x1 = max(x1, 0); y1 = max(y1, 0);
    unsigned box = (unsigned)x0 | ((unsigned)x1 << 8) | ((unsigned)y0 << 16) | ((unsigned)y1 << 24);

    ws[i] = pv2;  // depth
    float4* preA = (float4*)(ws + PN);
    float4* preB = (float4*)(ws + 5 * PN);
    preA[i] = make_float4(m2x, m2y, cA, cB);
    preB[i] = make_float4(cC, ops[i], colors[3 * i], colors[3 * i + 1]);
    ws[9 * PN + i] = colors[3 * i + 2];
    ((unsigned*)(ws + 10 * PN))[i] = box;
}

__global__ __launch_bounds__(256) void sort_scatter_kernel(float* __restrict__ ws)
{
    const float* dep = ws;
    const float4* d4 = (const float4*)ws;
    int lane = threadIdx.x & 63;
    int wid = threadIdx.x >> 6;
    int gbase = blockIdx.x * 16 + wid * 4;

    float di0 = dep[gbase], di1 = dep[gbase + 1], di2 = dep[gbase + 2], di3 = dep[gbase + 3];
    int r0 = 0, r1 = 0, r2 = 0, r3 = 0;
#pragma unroll 4
    for (int k = 0; k < 32; ++k) {
        int j4 = k * 64 + lane;
        float4 d = d4[j4];
        int jb = j4 * 4;
        r0 += (d.x < di0) || (d.x == di0 && (jb    ) < gbase);
        r0 += (d.y < di0) || (d.y == di0 && (jb + 1) < gbase);
        r0 += (d.z < di0) || (d.z == di0 && (jb + 2) < gbase);
        r0 += (d.w < di0) || (d.w == di0 && (jb + 3) < gbase);
        r1 += (d.x < di1) || (d.x == di1 && (jb    ) < gbase + 1);
        r1 += (d.y < di1) || (d.y == di1 && (jb + 1) < gbase + 1);
        r1 += (d.z < di1) || (d.z == di1 && (jb + 2) < gbase + 1);
        r1 += (d.w < di1) || (d.w == di1 && (jb + 3) < gbase + 1);
        r2 += (d.x < di2) || (d.x == di2 && (jb    ) < gbase + 2);
        r2 += (d.y < di2) || (d.y == di2 && (jb + 1) < gbase + 2);
        r2 += (d.z < di2) || (d.z == di2 && (jb + 2) < gbase + 2);
        r2 += (d.w < di2) || (d.w == di2 && (jb + 3) < gbase + 2);
        r3 += (d.x < di3) || (d.x == di3 && (jb    ) < gbase + 3);
        r3 += (d.y < di3) || (d.y == di3 && (jb + 1) < gbase + 3);
        r3 += (d.z < di3) || (d.z == di3 && (jb + 2) < gbase + 3);
        r3 += (d.w < di3) || (d.w == di3 && (jb + 3) < gbase + 3);
    }
#pragma unroll
    for (int off = 1; off < 64; off <<= 1) {
        r0 += __shfl_xor(r0, off);
        r1 += __shfl_xor(r1, off);
        r2 += __shfl_xor(r2, off);
        r3 += __shfl_xor(r3, off);
    }
    if (lane < 4) {
        int rk = (lane == 0) ? r0 : (lane == 1) ? r1 : (lane == 2) ? r2 : r3;
        int i = gbase + lane;
        const float4* preA = (const float4*)(ws + PN);
        const float4* preB = (const float4*)(ws + 5 * PN);
        float4* sA = (float4*)(ws + 11 * PN);
        float4* sB = (float4*)(ws + 15 * PN);
        sA[rk] = preA[i];
        sB[rk] = preB[i];
        ws[19 * PN + rk] = ws[9 * PN + i];
        ((unsigned*)(ws + 20 * PN))[rk] = ((const unsigned*)(ws + 10 * PN))[i];
    }
}

// 4 waves/block; wave w composes rank-chunks [8w, 8w+8); segments folded at end.
__global__ __launch_bounds__(256) void raster_kernel(
    const float* __restrict__ ws, const float* __restrict__ bg,
    float* __restrict__ out)
{
    __shared__ float4 lsA[4][256];          // 16 KB
    __shared__ float4 lsB[4][256];          // 16 KB
    __shared__ float  seg[4][64 * 4];       // 4 KB: per-wave (ar,ag,ab,T) per pixel
    __shared__ float  lsb[4][256];          // 4 KB
    volatile __shared__ float waveT[4];     // monotone-decreasing max-T per wave

    int tid = threadIdx.x;
    int lane = tid & 63, w = tid >> 6;
    int tileX = blockIdx.x & 31, tileY = blockIdx.x >> 5;
    int px = tileX * 8 + (lane & 7), py = tileY * 8 + (lane >> 3);
    float pxf = (float)px, pyf = (float)py;

    const float4* sA = (const float4*)(ws + 11 * PN);
    const float4* sB = (const float4*)(ws + 15 * PN);
    const float* sb = ws + 19 * PN;
    const unsigned* sbox = (const unsigned*)(ws + 20 * PN);

    if (tid < 4) waveT[tid] = 1.0f;
    __syncthreads();  // uniform

    float T = 1.0f, ar = 0.0f, ag = 0.0f, ab = 0.0f;

    for (int chunk = w * 8; chunk < w * 8 + 8; ++chunk) {
        // conservative cross-wave exit: product of predecessors' (stale, so
        // upper-bound) max-T; our whole remaining contribution scales by it.
        float pre = 1.0f;
        for (int q = 0; q < w; ++q) pre *= waveT[q];
        if (pre < 1e-4f) break;

        int base = chunk * 256;
        unsigned long long wv[4];
#pragma unroll
        for (int k = 0; k < 4; ++k) {
            unsigned bx = sbox[base + k * 64 + lane];
            bool ov = (tileX >= (int)(bx & 255)) & (tileX <= (int)((bx >> 8) & 255)) &
                      (tileY >= (int)((bx >> 16) & 255)) & (tileY <= (int)(bx >> 24));
            wv[k] = __ballot(ov);
        }
        if (!(wv[0] | wv[1] | wv[2] | wv[3])) continue;

        int cnt = 0;
#pragma unroll
        for (int k = 0; k < 4; ++k) {
            unsigned long long wk = wv[k];
            if ((wk >> lane) & 1ull) {
                int slot = cnt + (int)__popcll(wk & ((1ull << lane) - 1ull));
                int g = base + k * 64 + lane;
                lsA[w][slot] = sA[g];
                lsB[w][slot] = sB[g];
                lsb[w][slot] = sb[g];
            }
            cnt += (int)__popcll(wk);
        }
        // wave-local fence: LDS writes above visible to lockstep reads below
        asm volatile("s_waitcnt lgkmcnt(0)" ::: "memory");

        for (int j = 0; j < cnt; ++j) {
            float4 A = lsA[w][j];
            float4 B = lsB[w][j];
            float bcol = lsb[w][j];
            float dx = A.x - pxf, dy = A.y - pyf;
            float power = -0.5f * (A.z * dx * dx + B.x * dy * dy) - A.w * dx * dy;
            float alpha = fminf(0.99f, B.y * __expf(power));
            bool skip = (power > 0.0f) | (alpha < (1.0f / 255.0f));
            float a2 = skip ? 0.0f : alpha;
            float wgt = a2 * T;
            ar = fmaf(wgt, B.z, ar);
            ag = fmaf(wgt, B.w, ag);
            ab = fmaf(wgt, bcol, ab);
            T *= (1.0f - a2);
        }
        asm volatile("s_waitcnt lgkmcnt(0)" ::: "memory");  // WAR vs next compaction

        if (__all(T < 1e-5f)) break;  // segment residual <= 1e-5

        float tmax = T;
#pragma unroll
        for (int off = 1; off < 64; off <<= 1) tmax = fmaxf(tmax, __shfl_xor(tmax, off));
        if (lane == 0) waveT[w] = tmax;
    }

    // publish segment state (reuse own lsb region: this wave is done with it)
    seg[w][lane * 4 + 0] = ar;
    seg[w][lane * 4 + 1] = ag;
    seg[w][lane * 4 + 2] = ab;
    seg[w][lane * 4 + 3] = T;
    __syncthreads();  // uniform: every wave reaches here

    if (w == 0) {
        float A0 = 0.f, A1 = 0.f, A2 = 0.f, Tt = 1.f;
#pragma unroll
        for (int q = 0; q < 4; ++q) {
            A0 += Tt * seg[q][lane * 4 + 0];
            A1 += Tt * seg[q][lane * 4 + 1];
            A2 += Tt * seg[q][lane * 4 + 2];
            Tt *= seg[q][lane * 4 + 3];
        }
        int pidx = py * IW + px;
        out[pidx]               = A0 + Tt * bg[0];
        out[IH * IW + pidx]     = A1 + Tt * bg[1];
        out[2 * IH * IW + pidx] = A2 + Tt * bg[2];
    }
}

extern "C" void kernel_launch(void* const* d_in, const int* in_sizes, int n_in,
                              void* d_out, int out_size, void* d_ws, size_t ws_size,
                              hipStream_t stream) {
    const float* means  = (const float*)d_in[0];
    const float* colors = (const float*)d_in[1];
    const float* ops    = (const float*)d_in[2];
    const float* scales = (const float*)d_in[3];
    const float* rots   = (const float*)d_in[4];
    const float* bg     = (const float*)d_in[5];
    const float* viewm  = (const float*)d_in[6];
    const float* projm  = (const float*)d_in[7];
    float* out = (float*)d_out;
    float* ws  = (float*)d_ws;

    hipLaunchKernelGGL(preprocess_kernel, dim3(PN / 256), dim3(256), 0, stream,
                       means, colors, ops, scales, rots, viewm, projm, ws);
    hipLaunchKernelGGL(sort_scatter_kernel, dim3(PN / 16), dim3(256), 0, stream, ws);
    hipLaunchKernelGGL(raster_kernel, dim3(1024), dim3(256), 0, stream, ws, bg, out);
}